// Round 1
// baseline (368.425 us; speedup 1.0000x reference)
//
#include <hip/hip_runtime.h>
#include <hip/hip_fp16.h>
#include <math.h>

#define NN 100000
#define NE 3200000
#define CF 512

#define NPARTS  8
#define PART    12500              // nodes per partition (50 KB LDS hist)
#define NSLICES 64                 // edge slices
#define EPB     (NE / NSLICES)     // 50000 edges per block
#define NPB     (NSLICES * NPARTS) // 512 blocks -> 2 blocks/CU

// ---- ws layout (bytes) ----
// part : u16/half [NPB][PART] @ 0          (12,800,000) -- deg(u16) then s(half)
// h    : float[NN]            @ 12,800,000 (400,000)    -- x @ W^T (no dinv)
// g    : float[NN]            @ 13,200,000 (400,000)    -- h * dinv
// dinv : float[NN]            @ 13,600,000 (400,000)
#define OFF_H    12800000
#define OFF_G    13200000
#define OFF_DINV 13600000

// Per-wave int64-layout self-detect: for int64 input the high words of the
// first 64 words-pairs are all zero; for int32 they are edge values (~never
// all zero). Data is L1-hot after the first wave touches it.
__device__ __forceinline__ bool detect_f64(const int* __restrict__ e32) {
    unsigned v = ((const unsigned*)e32)[2 * (threadIdx.x & 63) + 1];
    return __ballot(v != 0u) == 0ULL;
}

// Load 4 consecutive cols starting at edge e (e % 4 == 0)
__device__ __forceinline__ int4 load_col4(const int* __restrict__ e32, bool f64, int e) {
    if (f64) {
        const int4* q = (const int4*)(e32 + 2 * (NE + e));  // 2 int64 per int4
        int4 a = q[0], b = q[1];
        return make_int4(a.x, a.z, b.x, b.z);
    }
    return *(const int4*)(e32 + NE + e);
}

// Load 4 consecutive rows starting at edge e (e % 4 == 0) -- unconditional,
// vector-wide: breaks the conditional row->gather dependent chain.
__device__ __forceinline__ int4 load_row4(const int* __restrict__ e32, bool f64, int e) {
    if (f64) {
        const int4* q = (const int4*)(e32 + 2 * e);
        int4 a = q[0], b = q[1];
        return make_int4(a.x, a.z, b.x, b.z);
    }
    return *(const int4*)(e32 + e);
}

// ---------------------------------------------------------------------------
// K1: fused deg-histogram + h = x @ W^T, wave-specialized.
//   waves 0..11 : LDS-privatized in-degree histogram (partition p, slice s)
//   waves 12..15: h for a contiguous 196-node range (wave-per-node dot, 2-node ILP)
// Same 512-block grid as before -> partition-siblings of a slice stay
// congruent mod 8 (same XCD L2) and fully co-resident.
// ---------------------------------------------------------------------------
#define NODES_PER_BLK 196   // 512 * 196 = 100352 >= NN

__global__ __launch_bounds__(1024) void deg_h_kernel(const int* __restrict__ e32,
                                                     const float* __restrict__ x,
                                                     const float* __restrict__ W,
                                                     unsigned short* __restrict__ deg_part,
                                                     float* __restrict__ h) {
    __shared__ int hist[PART];
    int tid = threadIdx.x;
    for (int i = tid; i < PART; i += 1024) hist[i] = 0;
    __syncthreads();

    int w = tid >> 6, lane = tid & 63;
    if (w < 12) {
        // ---- deg histogram over this block's edge slice ----
        bool f64 = detect_f64(e32);
        int p = blockIdx.x >> 6;
        int s = blockIdx.x & 63;
        int lo = p * PART;
        int base = s * EPB;
        // 768 lanes * 4 edges = stride 3072
        for (int e = base + tid * 4; e < base + EPB; e += 3072) {
            int4 c = load_col4(e32, f64, e);
            unsigned l0 = (unsigned)(c.x - lo), l1 = (unsigned)(c.y - lo);
            unsigned l2 = (unsigned)(c.z - lo), l3 = (unsigned)(c.w - lo);
            if (l0 < PART) atomicAdd(&hist[l0], 1);
            if (l1 < PART) atomicAdd(&hist[l1], 1);
            if (l2 < PART) atomicAdd(&hist[l2], 1);
            if (l3 < PART) atomicAdd(&hist[l3], 1);
        }
    } else {
        // ---- h = x @ W^T for nodes [blk*196, blk*196+196) ----
        const float4* Wr = (const float4*)W;
        float4 w0 = Wr[lane], w1 = Wr[lane + 64];   // invariant, hoisted
        int start = blockIdx.x * NODES_PER_BLK;
        int end = start + NODES_PER_BLK;
        for (int i = start + (w - 12) * 2; i < end; i += 8) {
            int i1 = i + 1;
            float s0 = 0.f, s1 = 0.f;
            if (i < NN) {
                const float4* xr = (const float4*)(x + (size_t)i * CF);
                float4 a = xr[lane], bq = xr[lane + 64];
                s0 = a.x * w0.x + a.y * w0.y + a.z * w0.z + a.w * w0.w
                   + bq.x * w1.x + bq.y * w1.y + bq.z * w1.z + bq.w * w1.w;
            }
            if (i1 < NN) {
                const float4* xr = (const float4*)(x + (size_t)i1 * CF);
                float4 a = xr[lane], bq = xr[lane + 64];
                s1 = a.x * w0.x + a.y * w0.y + a.z * w0.z + a.w * w0.w
                   + bq.x * w1.x + bq.y * w1.y + bq.z * w1.z + bq.w * w1.w;
            }
#pragma unroll
            for (int off = 32; off >= 1; off >>= 1) {
                s0 += __shfl_down(s0, off, 64);
                s1 += __shfl_down(s1, off, 64);
            }
            if (lane == 0) {
                if (i < NN) h[i] = s0;
                if (i1 < NN) h[i1] = s1;
            }
        }
    }
    __syncthreads();
    unsigned short* outp = deg_part + (size_t)blockIdx.x * PART;
    for (int i = tid; i < PART; i += 1024) outp[i] = (unsigned short)hist[i];
}

// K2: dinv[i] = rsqrt(1 + sum_slices deg_part[.][i]);  g[i] = h[i] * dinv[i]
__global__ void dinv_g_kernel(const unsigned short* __restrict__ deg_part,
                              const float* __restrict__ h,
                              float* __restrict__ dinv,
                              float* __restrict__ g) {
    int i = blockIdx.x * blockDim.x + threadIdx.x;
    if (i >= NN) return;
    int p = i / PART, l = i - p * PART;
    const unsigned short* bp = deg_part + ((size_t)(p << 6)) * PART + l;
    int d = 1;
#pragma unroll
    for (int s = 0; s < NSLICES; ++s) d += bp[(size_t)s * PART];
    float di = rsqrtf((float)d);
    dinv[i] = di;
    g[i] = h[i] * di;
}

// K3: edge scatter s[col] += g[row], LDS-privatized, half partials out.
// Rows prefetched unconditionally (int4-wide) so only the g-gather is
// conditional -> no 2-deep dependent load chain under divergent exec.
__global__ __launch_bounds__(1024) void scatter_lds_kernel(const int* __restrict__ e32,
                                                           const float* __restrict__ g,
                                                           __half* __restrict__ s_part) {
    __shared__ float hs[PART];
    int tid = threadIdx.x;
    for (int i = tid; i < PART; i += 1024) hs[i] = 0.f;
    __syncthreads();

    bool f64 = detect_f64(e32);
    int p = blockIdx.x >> 6;
    int s = blockIdx.x & 63;
    int lo = p * PART;
    int base = s * EPB;
    for (int e = base + tid * 4; e < base + EPB; e += 4096) {
        int4 c = load_col4(e32, f64, e);
        int4 r = load_row4(e32, f64, e);
        unsigned l0 = (unsigned)(c.x - lo), l1 = (unsigned)(c.y - lo);
        unsigned l2 = (unsigned)(c.z - lo), l3 = (unsigned)(c.w - lo);
        if (l0 < PART) atomicAdd(&hs[l0], g[r.x]);
        if (l1 < PART) atomicAdd(&hs[l1], g[r.y]);
        if (l2 < PART) atomicAdd(&hs[l2], g[r.z]);
        if (l3 < PART) atomicAdd(&hs[l3], g[r.w]);
    }
    __syncthreads();
    __half* outp = s_part + (size_t)blockIdx.x * PART;
    for (int i = tid; i < PART; i += 1024) outp[i] = __float2half(hs[i]);
}

// K4: out[i] = sigmoid(dinv[i] * (sum_slices s_part[.][i] + g[i]) + b)
__global__ void final_kernel(const __half* __restrict__ s_part,
                             const float* __restrict__ g,
                             const float* __restrict__ dinv,
                             const float* __restrict__ b,
                             float* __restrict__ out) {
    int i = blockIdx.x * blockDim.x + threadIdx.x;
    if (i >= NN) return;
    int p = i / PART, l = i - p * PART;
    const __half* bp = s_part + ((size_t)(p << 6)) * PART + l;
    float acc = g[i];
#pragma unroll
    for (int s = 0; s < NSLICES; ++s) acc += __half2float(bp[(size_t)s * PART]);
    float v = dinv[i] * acc + b[0];
    out[i] = 1.f / (1.f + expf(-v));
}

extern "C" void kernel_launch(void* const* d_in, const int* in_sizes, int n_in,
                              void* d_out, int out_size, void* d_ws, size_t ws_size,
                              hipStream_t stream) {
    const float* x = (const float*)d_in[0];
    const int* eidx = (const int*)d_in[1];
    const float* W = (const float*)d_in[2];
    const float* b = (const float*)d_in[3];
    float* out = (float*)d_out;

    char* ws = (char*)d_ws;
    unsigned short* part_u16 = (unsigned short*)(ws);  // deg partials (reused as half)
    __half* part_h = (__half*)(ws);
    float* h = (float*)(ws + OFF_H);
    float* g = (float*)(ws + OFF_G);
    float* dinv = (float*)(ws + OFF_DINV);

    deg_h_kernel<<<NPB, 1024, 0, stream>>>(eidx, x, W, part_u16, h);
    dinv_g_kernel<<<(NN + 255) / 256, 256, 0, stream>>>(part_u16, h, dinv, g);
    scatter_lds_kernel<<<NPB, 1024, 0, stream>>>(eidx, g, part_h);
    final_kernel<<<(NN + 255) / 256, 256, 0, stream>>>(part_h, g, dinv, b, out);
}